// Round 9
// baseline (595.136 us; speedup 1.0000x reference)
//
#include <hip/hip_runtime.h>
#include <hip/hip_bf16.h>

#define H 512
#define W 512
#define C 32
#define O 32
#define YP (H + 2)   // padded NHWC dims
#define XPD (W + 2)
#define ROWS 16      // rows per block in conv_nhwc

// fallback (R8) geometry
#define TW 64
#define SH 16
#define NS 4
#define RING 12
#define XCOLS (TW + 2)

using bf16x8 = __attribute__((ext_vector_type(8))) short;
using f32x4  = __attribute__((ext_vector_type(4))) float;

__device__ __forceinline__ unsigned short f2bf(float f) {
    union { float f; unsigned u; } c; c.f = f;
    unsigned r = c.u + 0x7fffu + ((c.u >> 16) & 1u);
    return (unsigned short)(r >> 16);
}

__device__ __forceinline__ uint4 pack8(const float* v) {
    uint4 pk;
    pk.x = (unsigned)f2bf(v[0]) | ((unsigned)f2bf(v[1]) << 16);
    pk.y = (unsigned)f2bf(v[2]) | ((unsigned)f2bf(v[3]) << 16);
    pk.z = (unsigned)f2bf(v[4]) | ((unsigned)f2bf(v[5]) << 16);
    pk.w = (unsigned)f2bf(v[6]) | ((unsigned)f2bf(v[7]) << 16);
    return pk;
}

// Reconstruct w[o, ci, 3, 3] from CP factors, store bf16 as w[s][o][ci].
__global__ void recon_w(const float* __restrict__ k0, const float* __restrict__ k1,
                        const float* __restrict__ k2, const float* __restrict__ k3,
                        unsigned short* __restrict__ wout) {
    int idx = blockIdx.x * 256 + threadIdx.x;
    if (idx >= 9 * 32 * 32) return;
    int ci = idx & 31;
    int o  = (idx >> 5) & 31;
    int s  = idx >> 10;
    int i = o >> 4, j = (o >> 2) & 3, k = o & 3;
    int a = ci >> 4, b = (ci >> 2) & 3, c = ci & 3;
    float acc = 0.f;
    #pragma unroll
    for (int r = 0; r < 8; ++r)
        acc += k0[(i*2 + a)*8 + r] * k1[(j*4 + b)*8 + r]
             * k2[(k*4 + c)*8 + r] * k3[s*8 + r];
    wout[idx] = f2bf(acc);
}

// ---- Pass 1: NCHW f32 -> padded NHWC bf16 ([n][yy][xx][ci], yy/xx have
// +1 zero border). Pure streaming transpose, no LDS: each thread handles
// (xx, ciq): gathers 8 channel dwords (1MB stride), packs one 16B store.
// Consecutive tid -> (ciq fast, xx next) => wave writes a dense 1KB line.
// Border tasks (gx/gy out of range) store zeros => conv needs NO bounds.
__launch_bounds__(256)
__global__ void to_nhwc(const float* __restrict__ x,
                        unsigned short* __restrict__ xp) {
    const int bid = blockIdx.x;          // 8*YP blocks: one padded row each
    const int n  = bid / YP;
    const int yy = bid - n * YP;
    const int gy = yy - 1;
    for (int t = threadIdx.x; t < XPD * 4; t += 256) {
        int ciq = t & 3;
        int xx  = t >> 2;
        int gx = xx - 1;
        bool inb = (gx >= 0) && (gx < W) && (gy >= 0) && (gy < H);
        const float* p = x + (((n*C + ciq*8)*H + gy)*W + gx);
        float v[8];
        #pragma unroll
        for (int j = 0; j < 8; ++j) v[j] = inb ? p[j * H * W] : 0.f;
        *(uint4*)&xp[(((n*YP + yy))*XPD + xx)*32 + ciq*8] = pack8(v);
    }
}

// ---- Pass 2: conv from padded NHWC bf16. NO LDS, NO barriers, NO bounds:
// per wave, 16-px x-segment; per row: 9 A-frags, each ONE coalesced 16B
// global load (wave covers a dense 1KB window; dy/dx overlaps hit L1/L2;
// the 135MB intermediate is L3-hot), 18 MFMA, 2 f32x4 stores. Pure
// dataflow — the barrier-phased strip machinery (stuck at 165-205us across
// R2..R8 regardless of traffic/occupancy) is gone.
__launch_bounds__(256, 3)
__global__ void conv_nhwc(const unsigned short* __restrict__ xp,
                          const unsigned short* __restrict__ wq,
                          const float* __restrict__ bias,
                          float* __restrict__ out) {
    const int tid = threadIdx.x;
    const int bid = ((blockIdx.x & 7) << 8) | (blockIdx.x >> 3);  // XCD swizzle
    const int n  = bid >> 8;            // 256 tiles/image (32 yb x 8 xb)
    const int yb = (bid >> 3) & 31;
    const int xb = bid & 7;
    const int y0 = yb * ROWS, x0 = xb * 64;

    const int lane = tid & 63;
    const int wave = tid >> 6;
    const int pix  = lane & 15;
    const int quad = lane >> 4;
    const int xs   = x0 + wave * 16;    // wave's output x-segment

    // B fragments: B[k=ci=quad*8+j][n=o=h*16+pix]
    bf16x8 bw[9][2];
    #pragma unroll
    for (int s = 0; s < 9; ++s)
        #pragma unroll
        for (int h = 0; h < 2; ++h)
            bw[s][h] = *(const bf16x8*)(wq + ((s*32 + h*16 + pix)*32 + quad*8));

    const float b0 = bias[pix];
    const float b1 = bias[16 + pix];

    for (int r = 0; r < ROWS; ++r) {
        const int gy = y0 + r;
        // A read base: element ((n*YP + gy+dy)*XPD + xs+pix+dx)*32 + quad*8
        // (padded coords: input pixel (gy+dy-1, x+dx-1) == xp[gy+dy][x+dx])
        const unsigned short* ap =
            xp + (((n*YP + gy))*XPD + xs + pix)*32 + quad*8;

        bf16x8 a[3][3];
        #pragma unroll
        for (int dy = 0; dy < 3; ++dy)
            #pragma unroll
            for (int dx = 0; dx < 3; ++dx)
                a[dy][dx] = *(const bf16x8*)(ap + (dy*XPD + dx)*32);

        f32x4 acc0 = {0.f, 0.f, 0.f, 0.f};
        f32x4 acc1 = {0.f, 0.f, 0.f, 0.f};
        __builtin_amdgcn_s_setprio(1);
        #pragma unroll
        for (int dy = 0; dy < 3; ++dy)
            #pragma unroll
            for (int dx = 0; dx < 3; ++dx) {
                const int stp = dy*3 + dx;
                acc0 = __builtin_amdgcn_mfma_f32_16x16x32_bf16(a[dy][dx], bw[stp][0], acc0, 0, 0, 0);
                acc1 = __builtin_amdgcn_mfma_f32_16x16x32_bf16(a[dy][dx], bw[stp][1], acc1, 0, 0, 0);
            }
        __builtin_amdgcn_s_setprio(0);

        // D: m = quad*4 + reg (pixel), n = pix (o)
        const int base0 = ((n*O + pix     ) * H + gy) * W + xs + quad*4;
        const int base1 = ((n*O + 16 + pix) * H + gy) * W + xs + quad*4;
        f32x4 o0 = acc0 + b0;
        f32x4 o1 = acc1 + b1;
        *(f32x4*)(out + base0) = o0;
        *(f32x4*)(out + base1) = o1;
    }
}

// ---- Fallback (R8): strip-pipelined LDS implicit-GEMM conv ----
__launch_bounds__(256, 3)
__global__ void conv_mfma(const float* __restrict__ x,
                          const unsigned short* __restrict__ wq,
                          const float* __restrict__ bias,
                          float* __restrict__ out) {
    __shared__ __align__(16) unsigned short sx[RING][XCOLS][C];

    const int tid = threadIdx.x;
    const int bid = ((blockIdx.x & 7) << 8) | (blockIdx.x >> 3);
    const int n  = bid >> 8;
    const int ty = (bid >> 3) & 31;
    const int tx = bid & 7;
    const int y0 = ty * SH, x0 = tx * TW;

    const int lane = tid & 63;
    const int wave = tid >> 6;
    const int pix  = lane & 15;
    const int quad = lane >> 4;

    bf16x8 bw[9][2];
    #pragma unroll
    for (int s = 0; s < 9; ++s)
        #pragma unroll
        for (int h = 0; h < 2; ++h)
            bw[s][h] = *(const bf16x8*)(wq + ((s*32 + h*16 + pix)*32 + quad*8));

    for (int task = tid; task < 6 * 4 * XCOLS; task += 256) {
        int gxl = task % XCOLS;
        int t2  = task / XCOLS;
        int ciq = t2 & 3;
        int r   = t2 >> 2;
        int gy = y0 - 1 + r;
        int gx = x0 + gxl - 1;
        bool inb = (gy >= 0) && (gx >= 0) && (gx < W);
        const float* p = x + (((n*C + ciq*8)*H + gy)*W + gx);
        float v[8];
        #pragma unroll
        for (int j2 = 0; j2 < 8; ++j2) v[j2] = inb ? p[j2 * H * W] : 0.f;
        int pos = ciq ^ ((gxl >> 1) & 3);
        *(uint4*)&sx[r][gxl][pos * 8] = pack8(v);
    }
    __syncthreads();

    const float b0 = bias[pix];
    const float b1 = bias[16 + pix];

    int rbase = 0;
    for (int s = 0; s < NS; ++s) {
        const bool more = (s + 1 < NS);
        float v[4][8];
        float vh[8];
        int hcol = 0, hciq = 0, hrow = 0;
        if (more) {
            #pragma unroll
            for (int k = 0; k < 4; ++k) {
                int gy = y0 + 4*s + 5 + k;
                bool inb = (gy < H);
                const float* p = x + (((n*C + wave*8)*H + gy)*W + x0 + lane);
                #pragma unroll
                for (int j2 = 0; j2 < 8; ++j2)
                    v[k][j2] = inb ? p[j2 * H * W] : 0.f;
            }
            if (tid < 32) {
                hcol = (tid & 1) ? (XCOLS - 1) : 0;
                hciq = (tid >> 1) & 3;
                hrow = tid >> 3;
                int gy = y0 + 4*s + 5 + hrow;
                int gx = x0 + hcol - 1;
                bool inb = (gy < H) && (gx >= 0) && (gx < W);
                const float* p = x + (((n*C + hciq*8)*H + gy)*W + gx);
                #pragma unroll
                for (int j2 = 0; j2 < 8; ++j2)
                    vh[j2] = inb ? p[j2 * H * W] : 0.f;
            }
        }
        __builtin_amdgcn_sched_barrier(0);

        const int gy_out = y0 + 4*s + wave;
        #pragma unroll
        for (int mt = 0; mt < 4; ++mt) {
            const int xm = mt << 4;
            f32x4 acc0 = {0.f, 0.f, 0.f, 0.f};
            f32x4 acc1 = {0.f, 0.f, 0.f, 0.f};
            __builtin_amdgcn_s_setprio(1);
            #pragma unroll
            for (int stp = 0; stp < 9; ++stp) {
                const int dy = stp / 3, dx = stp % 3;
                int sl = rbase + wave + dy; if (sl >= RING) sl -= RING;
                const int xp2 = xm + pix + dx;
                const int pos = quad ^ ((xp2 >> 1) & 3);
                bf16x8 a = *(const bf16x8*)&sx[sl][xp2][pos * 8];
                acc0 = __builtin_amdgcn_mfma_f32_16x16x32_bf16(a, bw[stp][0], acc0, 0, 0, 0);
                acc1 = __builtin_amdgcn_mfma_f32_16x16x32_bf16(a, bw[stp][1], acc1, 0, 0, 0);
            }
            __builtin_amdgcn_s_setprio(0);
            const int base0 = ((n*O + pix     ) * H + gy_out) * W + x0 + xm + quad*4;
            const int base1 = ((n*O + 16 + pix) * H + gy_out) * W + x0 + xm + quad*4;
            f32x4 o0 = acc0 + b0;
            f32x4 o1 = acc1 + b1;
            *(f32x4*)(out + base0) = o0;
            *(f32x4*)(out + base1) = o1;
        }

        if (more) {
            #pragma unroll
            for (int k = 0; k < 4; ++k) {
                int sl = rbase + 6 + k; if (sl >= RING) sl -= RING;
                int gxl = lane + 1;
                int pos = wave ^ ((gxl >> 1) & 3);
                *(uint4*)&sx[sl][gxl][pos * 8] = pack8(v[k]);
            }
            if (tid < 32) {
                int sl = rbase + 6 + hrow; if (sl >= RING) sl -= RING;
                int pos = hciq ^ ((hcol >> 1) & 3);
                *(uint4*)&sx[sl][hcol][pos * 8] = pack8(vh);
            }
            __syncthreads();
        }

        rbase += 4; if (rbase >= RING) rbase -= RING;
    }
}

extern "C" void kernel_launch(void* const* d_in, const int* in_sizes, int n_in,
                              void* d_out, int out_size, void* d_ws, size_t ws_size,
                              hipStream_t stream) {
    const float* x    = (const float*)d_in[0];
    const float* k0   = (const float*)d_in[1];
    const float* k1   = (const float*)d_in[2];
    const float* k2   = (const float*)d_in[3];
    const float* k3   = (const float*)d_in[4];
    const float* bias = (const float*)d_in[5];
    float* out = (float*)d_out;
    unsigned short* wbuf = (unsigned short*)d_ws;          // 9216 bf16 = 18 KB

    recon_w<<<36, 256, 0, stream>>>(k0, k1, k2, k3, wbuf);

    const size_t nhwc_bytes = (size_t)8 * YP * XPD * 32 * 2;   // ~135.3 MB
    const size_t need = 32768 + nhwc_bytes;
    if (ws_size >= need) {
        unsigned short* xph = (unsigned short*)((char*)d_ws + 32768);
        to_nhwc<<<8 * YP, 256, 0, stream>>>(x, xph);           // 4112 blocks
        conv_nhwc<<<2048, 256, 0, stream>>>(xph, wbuf, bias, out);
    } else {
        conv_mfma<<<2048, 256, 0, stream>>>(x, wbuf, bias, out);
    }
}

// Round 10
// 494.493 us; speedup vs baseline: 1.2035x; 1.2035x over previous
//
#include <hip/hip_runtime.h>
#include <hip/hip_bf16.h>

#define H 512
#define W 512
#define C 32
#define O 32
#define TW 64      // tile width (pixels)
#define SH 16      // rows per block (4 strips of 4)
#define NS 4       // strips per block
#define RING 12    // LDS row ring (read window 6 + write window 4 <= 12)
#define XCOLS (TW + 2)

using bf16x8 = __attribute__((ext_vector_type(8))) short;
using f32x4  = __attribute__((ext_vector_type(4))) float;

__device__ __forceinline__ unsigned short f2bf(float f) {
    union { float f; unsigned u; } c; c.f = f;
    unsigned r = c.u + 0x7fffu + ((c.u >> 16) & 1u);
    return (unsigned short)(r >> 16);
}

__device__ __forceinline__ uint4 pack8(const float* v) {
    uint4 pk;
    pk.x = (unsigned)f2bf(v[0]) | ((unsigned)f2bf(v[1]) << 16);
    pk.y = (unsigned)f2bf(v[2]) | ((unsigned)f2bf(v[3]) << 16);
    pk.z = (unsigned)f2bf(v[4]) | ((unsigned)f2bf(v[5]) << 16);
    pk.w = (unsigned)f2bf(v[6]) | ((unsigned)f2bf(v[7]) << 16);
    return pk;
}

// Reconstruct w[o, ci, 3, 3] from CP factors, store bf16 as w[s][o][ci]
// (ci contiguous => B-fragment loads are single 16B reads).
__global__ void recon_w(const float* __restrict__ k0, const float* __restrict__ k1,
                        const float* __restrict__ k2, const float* __restrict__ k3,
                        unsigned short* __restrict__ wout) {
    int idx = blockIdx.x * 256 + threadIdx.x;
    if (idx >= 9 * 32 * 32) return;
    int ci = idx & 31;
    int o  = (idx >> 5) & 31;
    int s  = idx >> 10;                 // 0..8 = dh*3+dw
    int i = o >> 4, j = (o >> 2) & 3, k = o & 3;
    int a = ci >> 4, b = (ci >> 2) & 3, c = ci & 3;
    float acc = 0.f;
    #pragma unroll
    for (int r = 0; r < 8; ++r)
        acc += k0[(i*2 + a)*8 + r] * k1[(j*4 + b)*8 + r]
             * k2[(k*4 + c)*8 + r] * k3[s*8 + r];
    wout[idx] = f2bf(acc);
}

// Strip-pipelined implicit-GEMM conv (R8 base = best measured family).
// R10 change: the strip's 33-load prefetch burst is SPLIT into four chunks
// interleaved into the mt compute loop (row k issued at sub-phase mt=k,
// pinned by sched_barrier(0) per chunk). Theory: all blocks chip-wide run
// identical phase lengths, so burst-issued loads queue at HBM while every
// wave then sits in vmcnt/barrier -> measured ~42% HBM duty across three
// structurally different kernels. Spreading issuance through the compute
// phase smooths chip-wide arrival; row-k still has >=1 sub-phase + pack
// distance of lead time. Register peak unchanged vs R8 (v[4][8] live to
// pack; VGPR 84, no spill).
__launch_bounds__(256, 3)
__global__ void conv_mfma(const float* __restrict__ x,
                          const unsigned short* __restrict__ wq,
                          const float* __restrict__ bias,
                          float* __restrict__ out) {
    // [ring-row][gx][ci-slot]; ci-quad slot XOR-swizzled by x (involution,
    // same on write and read) => ds_write_b128/ds_read_b128 bank-spread.
    __shared__ __align__(16) unsigned short sx[RING][XCOLS][C];

    const int tid = threadIdx.x;
    const int bid = ((blockIdx.x & 7) << 8) | (blockIdx.x >> 3);  // XCD swizzle
    const int n  = bid >> 8;            // 256 tiles per image (32 ty x 8 tx)
    const int ty = (bid >> 3) & 31;
    const int tx = bid & 7;
    const int y0 = ty * SH, x0 = tx * TW;

    const int lane = tid & 63;
    const int wave = tid >> 6;          // wave owns row (wave) of each strip
    const int pix  = lane & 15;
    const int quad = lane >> 4;

    // B fragments in registers (amortized over NS strips):
    // B[k=ci=quad*8+j][n=o=h*16+pix]
    bf16x8 bw[9][2];
    #pragma unroll
    for (int s = 0; s < 9; ++s)
        #pragma unroll
        for (int h = 0; h < 2; ++h)
            bw[s][h] = *(const bf16x8*)(wq + ((s*32 + h*16 + pix)*32 + quad*8));

    // ---- prologue: stage ring rows r=0..5 (gy = y0-1+r) ----
    for (int task = tid; task < 6 * 4 * XCOLS; task += 256) {
        int gxl = task % XCOLS;
        int t2  = task / XCOLS;
        int ciq = t2 & 3;
        int r   = t2 >> 2;              // 0..5 == ring slot
        int gy = y0 - 1 + r;            // < H always here
        int gx = x0 + gxl - 1;
        bool inb = (gy >= 0) && (gx >= 0) && (gx < W);
        const float* p = x + (((n*C + ciq*8)*H + gy)*W + gx);
        float v[8];
        #pragma unroll
        for (int j2 = 0; j2 < 8; ++j2) v[j2] = inb ? p[j2 * H * W] : 0.f;
        int pos = ciq ^ ((gxl >> 1) & 3);
        *(uint4*)&sx[r][gxl][pos * 8] = pack8(v);
    }
    __syncthreads();

    const float b0 = bias[pix];
    const float b1 = bias[16 + pix];

    int rbase = 0;
    for (int s = 0; s < NS; ++s) {
        const bool more = (s + 1 < NS);

        // staged registers for strip s+1's 4 new rows (+halo)
        float v[4][8];
        float vh[8];
        int hcol = 0, hciq = 0, hrow = 0;

        const int gy_out = y0 + 4*s + wave;
        #pragma unroll
        for (int mt = 0; mt < 4; ++mt) {
            // ---- interleaved issue: row k=mt of strip s+1 ----
            // main: wave w stages plane ciq=w, row k, col=lane (256B/row)
            if (more) {
                const int k = mt;
                int gy = y0 + 4*s + 5 + k;          // ring row rbase+6+k
                bool inb = (gy < H);                // uniform per wave
                const float* p = x + (((n*C + wave*8)*H + gy)*W + x0 + lane);
                #pragma unroll
                for (int j2 = 0; j2 < 8; ++j2)
                    v[k][j2] = inb ? p[j2 * H * W] : 0.f;
                // halo columns gxl in {0, XCOLS-1}: 32 tasks on threads 0..31
                if (mt == 0 && tid < 32) {
                    hcol = (tid & 1) ? (XCOLS - 1) : 0;
                    hciq = (tid >> 1) & 3;
                    hrow = tid >> 3;
                    int hgy = y0 + 4*s + 5 + hrow;
                    int hgx = x0 + hcol - 1;
                    bool hinb = (hgy < H) && (hgx >= 0) && (hgx < W);
                    const float* ph = x + (((n*C + hciq*8)*H + hgy)*W + hgx);
                    #pragma unroll
                    for (int j2 = 0; j2 < 8; ++j2)
                        vh[j2] = hinb ? ph[j2 * H * W] : 0.f;
                }
            }
            // Pin: this chunk's loads issue before this mt's MFMA cluster.
            __builtin_amdgcn_sched_barrier(0);

            // ---- compute sub-tile mt of strip s ----
            const int xm = mt << 4;
            f32x4 acc0 = {0.f, 0.f, 0.f, 0.f};
            f32x4 acc1 = {0.f, 0.f, 0.f, 0.f};
            __builtin_amdgcn_s_setprio(1);
            #pragma unroll
            for (int stp = 0; stp < 9; ++stp) {
                const int dy = stp / 3, dx = stp % 3;   // const-folded
                int sl = rbase + wave + dy; if (sl >= RING) sl -= RING;
                const int xp = xm + pix + dx;
                const int pos = quad ^ ((xp >> 1) & 3); // same involution
                bf16x8 a = *(const bf16x8*)&sx[sl][xp][pos * 8];
                acc0 = __builtin_amdgcn_mfma_f32_16x16x32_bf16(a, bw[stp][0], acc0, 0, 0, 0);
                acc1 = __builtin_amdgcn_mfma_f32_16x16x32_bf16(a, bw[stp][1], acc1, 0, 0, 0);
            }
            __builtin_amdgcn_s_setprio(0);
            // D: m = quad*4 + reg (pixel), n = pix (o)
            const int base0 = ((n*O + pix     ) * H + gy_out) * W + x0 + xm + quad*4;
            const int base1 = ((n*O + 16 + pix) * H + gy_out) * W + x0 + xm + quad*4;
            f32x4 o0 = acc0 + b0;
            f32x4 o1 = acc1 + b1;
            *(f32x4*)(out + base0) = o0;
            *(f32x4*)(out + base1) = o1;
        }

        // ---- pack + ds_write staged rows into ring slots rbase+6..rbase+9 ----
        // (disjoint from read window rbase..rbase+5 mod 12; prior readers of
        // these slots passed the previous barrier)
        if (more) {
            #pragma unroll
            for (int k = 0; k < 4; ++k) {
                int sl = rbase + 6 + k; if (sl >= RING) sl -= RING;
                int gxl = lane + 1;
                int pos = wave ^ ((gxl >> 1) & 3);
                *(uint4*)&sx[sl][gxl][pos * 8] = pack8(v[k]);
            }
            if (tid < 32) {
                int sl = rbase + 6 + hrow; if (sl >= RING) sl -= RING;
                int pos = hciq ^ ((hcol >> 1) & 3);
                *(uint4*)&sx[sl][hcol][pos * 8] = pack8(vh);
            }
            __syncthreads();
        }

        rbase += 4; if (rbase >= RING) rbase -= RING;
    }
}

extern "C" void kernel_launch(void* const* d_in, const int* in_sizes, int n_in,
                              void* d_out, int out_size, void* d_ws, size_t ws_size,
                              hipStream_t stream) {
    const float* x    = (const float*)d_in[0];
    const float* k0   = (const float*)d_in[1];
    const float* k1   = (const float*)d_in[2];
    const float* k2   = (const float*)d_in[3];
    const float* k3   = (const float*)d_in[4];
    const float* bias = (const float*)d_in[5];
    float* out = (float*)d_out;
    unsigned short* wbuf = (unsigned short*)d_ws;  // 9216 bf16 = 18 KB

    recon_w<<<36, 256, 0, stream>>>(k0, k1, k2, k3, wbuf);
    // 8 images * (512/SH=32) * (512/TW=8) = 2048 blocks
    conv_mfma<<<2048, 256, 0, stream>>>(x, wbuf, bias, out);
}